// Round 4
// baseline (407.345 us; speedup 1.0000x reference)
//
#include <hip/hip_runtime.h>

// R4: shifted-copy z-image + Tc=2 time chunking.
// Block = 256 thr = 4 waves = 4 samples. GEMM per chunk (2 steps):
// C[64oc x 96] = W[64x208(->224)] * B, columns n = t*48 + slz*9 + pos
// (48-pad per t so both t's of a LIF2 neuron live in the SAME lane).
// Spike storage: per (sl,ic,y) row, 3 overlapping 8B bf16 copies
// (z[0..3], z[1..4], z[2..5]) at byte ic*24 + copy*8; row stride 336 B
// (ic dim padded to 14; ic=13 zeroed once = K-padding 208->224 for free).
// B-frag = two ds_read_b64 at +kt*48 / +kt*48+336 (compiler merges to
// ds_read2_b64). Scatter = 3 unconditional b64 stores/row/step, bank
// stride 6*ic mod 32 -> all distinct -> ~conflict-free.
// Weights: 3-way bf16 split (fp32-grade), A-frags static in registers.
// MFMA layouts (learn_hip m89/m91): A[m][k]: m=lane&15,k=quad*8+j;
// B[k][n]: n=lane&15,k=quad*8+j; C/D: col=lane&15,row=quad*4+reg.

#define NSTEPS 100
#define NCHUNK 50
// z-image byte strides
#define COPYB 8
#define ICB   24
#define YB    336
#define SLB   2016
#define BUFB  8064

typedef __attribute__((ext_vector_type(8))) short bf16x8;
typedef __attribute__((ext_vector_type(4))) float f32x4;
typedef __attribute__((ext_vector_type(4))) unsigned int u32x4;

__device__ __forceinline__ unsigned short f2bf(float f) {
    unsigned u = __float_as_uint(f);
    unsigned r = ((u >> 16) & 1u) + 0x7FFFu;
    return (unsigned short)((u + r) >> 16);
}
__device__ __forceinline__ float bf2f(unsigned short h) {
    return __uint_as_float(((unsigned)h) << 16);
}

// conv1 + 2x2 maxpool for one spike-row (sample, ic, y): 6 outputs
__device__ __forceinline__ void conv1_row(const float* __restrict__ xs,
                                          const float* __restrict__ w1s,
                                          float b1v, int y, float* cur) {
    float cr[2][12];
    #pragma unroll
    for (int rr = 0; rr < 2; ++rr) {
        const int cy = 2 * y + rr;
        #pragma unroll
        for (int cx = 0; cx < 12; ++cx) {
            float a = 0.f;
            #pragma unroll
            for (int ky = 0; ky < 4; ++ky)
            #pragma unroll
            for (int kx = 0; kx < 4; ++kx)
                a = fmaf(xs[(cy + ky) * 16 + cx + kx], w1s[ky * 4 + kx], a);
            cr[rr][cx] = a + b1v;
        }
    }
    #pragma unroll
    for (int px = 0; px < 6; ++px)
        cur[px] = fmaxf(fmaxf(cr[0][2 * px], cr[0][2 * px + 1]),
                        fmaxf(cr[1][2 * px], cr[1][2 * px + 1]));
}

// One LIF1 step for a row: update state, store 3 shifted 8B copies.
__device__ __forceinline__ void lif1_step(float* v1, float* i1, const float* cur,
                                          unsigned char* wb) {
    unsigned zb[6];
    #pragma unroll
    for (int xx = 0; xx < 6; ++xx) {
        const float vd = v1[xx] + 0.1f * (i1[xx] - v1[xx]);
        i1[xx] = i1[xx] * 0.8f + cur[xx];
        const bool sp = vd > 1.0f;
        v1[xx] = sp ? 0.0f : vd;
        zb[xx] = sp ? 0x3F80u : 0u;     // bf16 1.0
    }
    const unsigned a01 = zb[0] | (zb[1] << 16);
    const unsigned a12 = zb[1] | (zb[2] << 16);
    const unsigned a23 = zb[2] | (zb[3] << 16);
    const unsigned a34 = zb[3] | (zb[4] << 16);
    const unsigned a45 = zb[4] | (zb[5] << 16);
    *(uint2*)(wb)      = make_uint2(a01, a23);   // copy0: z0..z3
    *(uint2*)(wb + 8)  = make_uint2(a12, a34);   // copy1: z1..z4
    *(uint2*)(wb + 16) = make_uint2(a23, a45);   // copy2: z2..z5
}

__device__ __forceinline__ bf16x8 ldfrag(const unsigned char* p) {
    const uint2 h0 = *(const uint2*)(p);
    const uint2 h1 = *(const uint2*)(p + YB);    // next ky row
    u32x4 u = {h0.x, h0.y, h1.x, h1.y};
    return __builtin_bit_cast(bf16x8, u);
}

__global__ __launch_bounds__(256, 2)
void snn_kernel(const float* __restrict__ x,
                const float* __restrict__ w1,
                const float* __restrict__ b1,
                const float* __restrict__ w2,
                const float* __restrict__ b2,
                const float* __restrict__ wf,
                const float* __restrict__ bf,
                float* __restrict__ out, int B)
{
    __shared__ __align__(16) unsigned char s_zi[2 * BUFB];  // 16128 B, 2 t-buffers
    __shared__ __align__(16) float s_z2[2 * 4 * 576];       // 18432 B (t, sample); also x scratch
    __shared__ __align__(16) float s_w1[13 * 16];
    __shared__ float s_b1[13];

    const int tid  = threadIdx.x;
    const int wave = tid >> 6, lane = tid & 63;
    const int quad = lane >> 4, col = lane & 15;

    // ---- stage x into s_z2 scratch; stage w1/b1; zero ic=13 K-pad rows ----
    ((float4*)(s_z2 + wave * 256))[lane] =
        ((const float4*)(x + (size_t)(blockIdx.x * 4 + wave) * 256))[lane];
    if (tid < 208) s_w1[tid] = w1[tid];
    if (tid < 13)  s_b1[tid] = b1[tid];
    if (tid < 144) {                     // 2 bufs * 4 sl * 6 y * 3 copies
        const int q = tid % 3, row = tid / 3;
        const int buf = row / 24, r2 = row % 24, sl = r2 / 6, y = r2 % 6;
        *(uint2*)(s_zi + buf * BUFB + sl * SLB + y * YB + 13 * ICB + q * COPYB) =
            make_uint2(0u, 0u);
    }
    __syncthreads();

    // ---- LIF1 row ownership: rows R = tid and tid+256 of 312 = 4*13*6 ----
    int sA, icA, yA, sB = 0, icB = 0, yB2 = 0;
    { const int R = tid;       sA = R / 78; int r = R - 78 * sA; icA = r / 6; yA = r - 6 * icA; }
    if (tid < 56) { const int R = tid + 256; sB = R / 78; int r = R - 78 * sB; icB = r / 6; yB2 = r - 6 * icB; }

    float cur1a[6], v1a[6], i1a[6], cur1b[6], v1b[6], i1b[6];
    conv1_row(s_z2 + sA * 256, s_w1 + icA * 16, s_b1[icA], yA, cur1a);
    if (tid < 56) conv1_row(s_z2 + sB * 256, s_w1 + icB * 16, s_b1[icB], yB2, cur1b);
    #pragma unroll
    for (int j = 0; j < 6; ++j) { v1a[j] = i1a[j] = 0.f; v1b[j] = i1b[j] = 0.f; }

    unsigned char* wbA = s_zi + sA * SLB + yA * YB + icA * ICB;
    unsigned char* wbB = s_zi + sB * SLB + yB2 * YB + icB * ICB;

    // ---- A-fragments: 3-way bf16 split of w2 rows, static in registers ----
    bf16x8 Ahi[7], Amid[7], Alo[7];
    {
        const float* wrow = w2 + (size_t)(wave * 16 + col) * 208;
        #pragma unroll
        for (int kt = 0; kt < 7; ++kt) {
            const int k0 = kt * 32 + quad * 8;
            bf16x8 h, m, l;
            #pragma unroll
            for (int j = 0; j < 8; ++j) {
                const int k = k0 + j;
                const float w = (k < 208) ? wrow[k] : 0.f;
                const unsigned short hb = f2bf(w);  const float r1 = w - bf2f(hb);
                const unsigned short mb = f2bf(r1); const float r2 = r1 - bf2f(mb);
                const unsigned short lb = f2bf(r2);
                h[j] = (short)hb; m[j] = (short)mb; l[j] = (short)lb;
            }
            Ahi[kt] = h; Amid[kt] = m; Alo[kt] = l;
        }
    }

    // ---- static per-lane: fc weights, b2, B-frag base ptrs, z2 write ptrs ----
    float wf0[9], wf1[9];
    #pragma unroll
    for (int q = 0; q < 9; ++q) { wf0[q] = wf[lane + 64 * q]; wf1[q] = wf[576 + lane + 64 * q]; }
    const float bfv0 = bf[0], bfv1 = bf[1];
    float b2r[4];
    #pragma unroll
    for (int r = 0; r < 4; ++r) b2r[r] = b2[wave * 16 + quad * 4 + r];

    const unsigned char* bp[3];   // per jt-tile B base (t0 buffer; t1 = +BUFB offset)
    float* zwp[3];
    bool zv[3];
    #pragma unroll
    for (int jt = 0; jt < 3; ++jt) {
        const int n = jt * 16 + col;          // n' in [0,48); valid < 36
        const int slz = n / 9, pos = n - 9 * slz, py = pos / 3, px = pos - 3 * py;
        bp[jt] = s_zi + slz * SLB + py * YB + px * COPYB
                      + (quad & 1) * (2 * YB) + (quad >> 1) * ICB;
        zv[jt] = (n < 36);
        zwp[jt] = s_z2 + slz * 576 + (wave * 16 + quad * 4) * 9 + pos;
    }

    float v2[12], i2[12];
    #pragma unroll
    for (int p = 0; p < 12; ++p) { v2[p] = 0.f; i2[p] = 0.f; }
    float v3a = 0.f, i3a = 0.f, v3b = 0.f, i3b = 0.f, sum0 = 0.f, sum1 = 0.f;

    const int sG = blockIdx.x * 4 + wave;
    float* outv = out + (size_t)2 * B;
    __syncthreads();

    #pragma unroll 1
    for (int ch = 0; ch < NCHUNK; ++ch) {
        // ---- Phase A: LIF1 x2 steps, store into the two z-image buffers ----
        lif1_step(v1a, i1a, cur1a, wbA);
        lif1_step(v1a, i1a, cur1a, wbA + BUFB);
        if (tid < 56) {
            lif1_step(v1b, i1b, cur1b, wbB);
            lif1_step(v1b, i1b, cur1b, wbB + BUFB);
        }
        __syncthreads();

        // ---- Phase B: GEMM, 6 accumulator chains (3 jt-tiles x 2 t) ----
        f32x4 c0 = {0.f,0.f,0.f,0.f}, c1 = c0, c2 = c0, c3 = c0, c4 = c0, c5 = c0;
        #pragma unroll
        for (int kt = 0; kt < 7; ++kt) {
            const int ko = kt * 48;
            const bf16x8 b0 = ldfrag(bp[0] + ko);
            const bf16x8 b1f = ldfrag(bp[1] + ko);
            const bf16x8 b2f = ldfrag(bp[2] + ko);
            const bf16x8 b3 = ldfrag(bp[0] + ko + BUFB);
            const bf16x8 b4 = ldfrag(bp[1] + ko + BUFB);
            const bf16x8 b5 = ldfrag(bp[2] + ko + BUFB);
            c0 = __builtin_amdgcn_mfma_f32_16x16x32_bf16(Alo[kt],  b0,  c0, 0, 0, 0);
            c1 = __builtin_amdgcn_mfma_f32_16x16x32_bf16(Alo[kt],  b1f, c1, 0, 0, 0);
            c2 = __builtin_amdgcn_mfma_f32_16x16x32_bf16(Alo[kt],  b2f, c2, 0, 0, 0);
            c3 = __builtin_amdgcn_mfma_f32_16x16x32_bf16(Alo[kt],  b3,  c3, 0, 0, 0);
            c4 = __builtin_amdgcn_mfma_f32_16x16x32_bf16(Alo[kt],  b4,  c4, 0, 0, 0);
            c5 = __builtin_amdgcn_mfma_f32_16x16x32_bf16(Alo[kt],  b5,  c5, 0, 0, 0);
            c0 = __builtin_amdgcn_mfma_f32_16x16x32_bf16(Amid[kt], b0,  c0, 0, 0, 0);
            c1 = __builtin_amdgcn_mfma_f32_16x16x32_bf16(Amid[kt], b1f, c1, 0, 0, 0);
            c2 = __builtin_amdgcn_mfma_f32_16x16x32_bf16(Amid[kt], b2f, c2, 0, 0, 0);
            c3 = __builtin_amdgcn_mfma_f32_16x16x32_bf16(Amid[kt], b3,  c3, 0, 0, 0);
            c4 = __builtin_amdgcn_mfma_f32_16x16x32_bf16(Amid[kt], b4,  c4, 0, 0, 0);
            c5 = __builtin_amdgcn_mfma_f32_16x16x32_bf16(Amid[kt], b5,  c5, 0, 0, 0);
            c0 = __builtin_amdgcn_mfma_f32_16x16x32_bf16(Ahi[kt],  b0,  c0, 0, 0, 0);
            c1 = __builtin_amdgcn_mfma_f32_16x16x32_bf16(Ahi[kt],  b1f, c1, 0, 0, 0);
            c2 = __builtin_amdgcn_mfma_f32_16x16x32_bf16(Ahi[kt],  b2f, c2, 0, 0, 0);
            c3 = __builtin_amdgcn_mfma_f32_16x16x32_bf16(Ahi[kt],  b3,  c3, 0, 0, 0);
            c4 = __builtin_amdgcn_mfma_f32_16x16x32_bf16(Ahi[kt],  b4,  c4, 0, 0, 0);
            c5 = __builtin_amdgcn_mfma_f32_16x16x32_bf16(Ahi[kt],  b5,  c5, 0, 0, 0);
        }

        // ---- Phase B2: LIF2 (t0 then t1 per neuron, same lane) + z2 export ----
        const f32x4 ct0[3] = {c0, c1, c2};
        const f32x4 ct1[3] = {c3, c4, c5};
        #pragma unroll
        for (int jt = 0; jt < 3; ++jt) {
            #pragma unroll
            for (int r = 0; r < 4; ++r) {
                const int p = jt * 4 + r;
                float vd = v2[p] + 0.1f * (i2[p] - v2[p]);
                i2[p] = i2[p] * 0.8f + (ct0[jt][r] + b2r[r]);
                bool sp = vd > 1.0f;
                v2[p] = sp ? 0.0f : vd;
                if (zv[jt]) zwp[jt][9 * r] = sp ? 1.0f : 0.0f;
                vd = v2[p] + 0.1f * (i2[p] - v2[p]);
                i2[p] = i2[p] * 0.8f + (ct1[jt][r] + b2r[r]);
                sp = vd > 1.0f;
                v2[p] = sp ? 0.0f : vd;
                if (zv[jt]) zwp[jt][9 * r + 2304] = sp ? 1.0f : 0.0f;
            }
        }
        __syncthreads();

        // ---- Phase C: fc + LIF3 for t0, t1 (wave = its sample) ----
        #pragma unroll
        for (int tl = 0; tl < 2; ++tl) {
            const float* zs = s_z2 + tl * 2304 + wave * 576;
            float p0 = 0.f, p1 = 0.f;
            #pragma unroll
            for (int q = 0; q < 9; ++q) {
                const float z = zs[lane + 64 * q];
                p0 = fmaf(z, wf0[q], p0);
                p1 = fmaf(z, wf1[q], p1);
            }
            #pragma unroll
            for (int off = 32; off > 0; off >>= 1) {
                p0 += __shfl_xor(p0, off);
                p1 += __shfl_xor(p1, off);
            }
            const float c3a = p0 + bfv0, c3b = p1 + bfv1;
            const float vd0 = v3a + 0.1f * (i3a - v3a);
            const float vd1 = v3b + 0.1f * (i3b - v3b);
            i3a = i3a * 0.8f + c3a;
            i3b = i3b * 0.8f + c3b;
            const bool q0 = vd0 > 1.0f, q1 = vd1 > 1.0f;
            v3a = q0 ? 0.0f : vd0;
            v3b = q1 ? 0.0f : vd1;
            sum0 += q0 ? 1.0f : 0.0f;
            sum1 += q1 ? 1.0f : 0.0f;
            if (lane == 0)
                *(float2*)(outv + (size_t)(2 * ch + tl) * 2 * B + 2 * sG) =
                    make_float2(v3a, v3b);
        }
    }

    if (lane == 0)
        *(float2*)(out + (size_t)2 * sG) = make_float2(sum0, sum1);
}

extern "C" void kernel_launch(void* const* d_in, const int* in_sizes, int n_in,
                              void* d_out, int out_size, void* d_ws, size_t ws_size,
                              hipStream_t stream)
{
    const float* x  = (const float*)d_in[0];
    const float* w1 = (const float*)d_in[1];
    const float* b1 = (const float*)d_in[2];
    const float* w2 = (const float*)d_in[3];
    const float* b2 = (const float*)d_in[4];
    const float* wf = (const float*)d_in[5];
    const float* bf = (const float*)d_in[6];
    float* out = (float*)d_out;

    const int B = in_sizes[0] / 256;     // x is [B,1,16,16]
    const int grid = B / 4;              // 4 samples per block

    hipLaunchKernelGGL(snn_kernel, dim3(grid), dim3(256), 0, stream,
                       x, w1, b1, w2, b2, wf, bf, out, B);
}

// Round 5
// 305.768 us; speedup vs baseline: 1.3322x; 1.3322x over previous
//
#include <hip/hip_runtime.h>

// R5 = R3's proven layouts + single barrier per step + deferred Phase C.
// Block = 256 thr = 4 waves. GEMM is block-cooperative: wave w owns oc-tile
// [16w,16w+16) for all 4 samples; Phase C: wave w = sample w's fc/LIF3.
// Step order:  A(t): LIF1 -> zimg[t&1]   (all threads)
//              __syncthreads()           (the ONLY barrier per step)
//              C(t-1): fc+LIF3 from s_z2[(t-1)&1]   (overlaps B's loads)
//              B(t): GEMM from zimg[t&1] -> LIF2 -> s_z2[t&1]
// Hazards: A(t+1) WAR vs B(t-1) reads (same-parity zimg) crosses barrier(t);
// C(t-1) RAW on B(t-1)'s z2 writes crosses barrier(t). All others: disjoint
// parity. Final C(99) after a trailing barrier.
// MFMA layouts (m89/m91): A[m][k]: m=lane&15,k=quad*8+j; B[k][n] same;
// C/D: col=lane&15, row=quad*4+reg. Weights: 3-way bf16 split (fp32-grade).

#define NSTEPS 100
#define IMSTRIDE 464           // 116 words; b128 reads sit on 4-aligned bank slots
#define ZIMG (48 * IMSTRIDE)   // 22272 B per t-parity buffer

typedef __attribute__((ext_vector_type(8))) short bf16x8;
typedef __attribute__((ext_vector_type(4))) float f32x4;

__device__ __forceinline__ unsigned short f2bf(float f) {
    unsigned u = __float_as_uint(f);
    unsigned r = ((u >> 16) & 1u) + 0x7FFFu;
    return (unsigned short)((u + r) >> 16);
}
__device__ __forceinline__ float bf2f(unsigned short h) {
    return __uint_as_float(((unsigned)h) << 16);
}

// conv1 + 2x2 maxpool for one spike-row (sample, ic, y): 6 outputs
__device__ __forceinline__ void conv1_row(const float* __restrict__ xs,
                                          const float* __restrict__ w1s,
                                          float b1v, int y, float* cur) {
    float cr[2][12];
    #pragma unroll
    for (int rr = 0; rr < 2; ++rr) {
        const int cy = 2 * y + rr;
        #pragma unroll
        for (int cx = 0; cx < 12; ++cx) {
            float a = 0.f;
            #pragma unroll
            for (int ky = 0; ky < 4; ++ky)
            #pragma unroll
            for (int kx = 0; kx < 4; ++kx)
                a = fmaf(xs[(cy + ky) * 16 + cx + kx], w1s[ky * 4 + kx], a);
            cr[rr][cx] = a + b1v;
        }
    }
    #pragma unroll
    for (int px = 0; px < 6; ++px)
        cur[px] = fmaxf(fmaxf(cr[0][2 * px], cr[0][2 * px + 1]),
                        fmaxf(cr[1][2 * px], cr[1][2 * px + 1]));
}

// LIF1 for one spike-row + scatter bf16 quads into im2col rows (R3 layout)
__device__ __forceinline__ void lif1_row(float* v1, float* i1, const float* cur,
                                         unsigned char* s_im, int sl, int ic, int y) {
    unsigned zb[6];
    #pragma unroll
    for (int xx = 0; xx < 6; ++xx) {
        const float vd = v1[xx] + 0.1f * (i1[xx] - v1[xx]);
        i1[xx] = i1[xx] * 0.8f + cur[xx];
        const bool sp = vd > 1.0f;
        v1[xx] = sp ? 0.0f : vd;
        zb[xx] = sp ? 0x3F80u : 0u;     // bf16 1.0 bits
    }
    const unsigned p0 = zb[0] | (zb[1] << 16);
    const unsigned p1 = zb[1] | (zb[2] << 16);
    const unsigned p2 = zb[2] | (zb[3] << 16);
    const unsigned p3 = zb[3] | (zb[4] << 16);
    const unsigned p4 = zb[4] | (zb[5] << 16);
    const uint2 q0 = make_uint2(p0, p2);   // z[0..3]
    const uint2 q1 = make_uint2(p1, p3);   // z[1..4]
    const uint2 q2 = make_uint2(p2, p4);   // z[2..5]
    unsigned char* rowk = s_im + ic * 32;
    #pragma unroll
    for (int ky = 0; ky < 4; ++ky) {
        const int py = y - ky;
        if (0 <= py && py <= 2) {
            unsigned char* b = rowk + (sl * 9 + py * 3) * IMSTRIDE + ky * 8;
            *(uint2*)(b) = q0;                    // px = 0
            *(uint2*)(b + IMSTRIDE) = q1;         // px = 1
            *(uint2*)(b + 2 * IMSTRIDE) = q2;     // px = 2
        }
    }
}

__global__ __launch_bounds__(256, 2)
void snn_kernel(const float* __restrict__ x,
                const float* __restrict__ w1,
                const float* __restrict__ b1,
                const float* __restrict__ w2,
                const float* __restrict__ b2,
                const float* __restrict__ wf,
                const float* __restrict__ bf,
                float* __restrict__ out, int B)
{
    __shared__ __align__(16) unsigned char s_im[2 * ZIMG];   // 44544 B
    __shared__ __align__(16) float s_z2[2 * 2304];           // 18432 B; buf0 also x scratch
    __shared__ __align__(16) float s_w1[13 * 16];
    __shared__ float s_b1[13];

    const int tid  = threadIdx.x;
    const int wave = tid >> 6, lane = tid & 63;
    const int quad = lane >> 4, col = lane & 15;

    // ---- stage x into s_z2[buf0] scratch; stage w1/b1; zero both im buffers ----
    ((float4*)(s_z2 + wave * 256))[lane] =
        ((const float4*)(x + (size_t)(blockIdx.x * 4 + wave) * 256))[lane];
    if (tid < 208) s_w1[tid] = w1[tid];
    if (tid < 13)  s_b1[tid] = b1[tid];
    for (int i = tid; i < 2 * ZIMG / 16; i += 256)
        ((uint4*)s_im)[i] = make_uint4(0, 0, 0, 0);
    __syncthreads();

    // ---- LIF1 row ownership: rows R = tid and tid+256 of 312 = 4*13*6 ----
    int sA, icA, yA, sB = 0, icB = 0, yB = 0;
    { const int R = tid;       sA = R / 78; int r = R - 78 * sA; icA = r / 6; yA = r - 6 * icA; }
    if (tid < 56) { const int R = tid + 256; sB = R / 78; int r = R - 78 * sB; icB = r / 6; yB = r - 6 * icB; }

    float cur1a[6], v1a[6], i1a[6], cur1b[6], v1b[6], i1b[6];
    conv1_row(s_z2 + sA * 256, s_w1 + icA * 16, s_b1[icA], yA, cur1a);
    if (tid < 56) conv1_row(s_z2 + sB * 256, s_w1 + icB * 16, s_b1[icB], yB, cur1b);
    #pragma unroll
    for (int j = 0; j < 6; ++j) { v1a[j] = i1a[j] = 0.f; v1b[j] = i1b[j] = 0.f; }

    // ---- A-fragments: 3-way bf16 split of w2 rows, static in registers ----
    bf16x8 Ahi[7], Amid[7], Alo[7];
    {
        const float* wrow = w2 + (size_t)(wave * 16 + col) * 208;
        #pragma unroll
        for (int kt = 0; kt < 7; ++kt) {
            const int k0 = kt * 32 + quad * 8;
            bf16x8 h, m, l;
            #pragma unroll
            for (int j = 0; j < 8; ++j) {
                const int k = k0 + j;
                const float w = (k < 208) ? wrow[k] : 0.f;
                const unsigned short hb = f2bf(w);  const float r1 = w - bf2f(hb);
                const unsigned short mb = f2bf(r1); const float r2 = r1 - bf2f(mb);
                const unsigned short lb = f2bf(r2);
                h[j] = (short)hb; m[j] = (short)mb; l[j] = (short)lb;
            }
            Ahi[kt] = h; Amid[kt] = m; Alo[kt] = l;
        }
    }

    // ---- static per-lane: fc weights, b2, B-frag ptrs, z2 write ptrs ----
    float wf0[9], wf1[9];
    #pragma unroll
    for (int q = 0; q < 9; ++q) { wf0[q] = wf[lane + 64 * q]; wf1[q] = wf[576 + lane + 64 * q]; }
    const float bfv0 = bf[0], bfv1 = bf[1];
    float b2r[4];
    #pragma unroll
    for (int r = 0; r < 4; ++r) b2r[r] = b2[wave * 16 + quad * 4 + r];

    const unsigned char* bp[3];
    float* zwp[3];
    bool zv[3];
    #pragma unroll
    for (int nt = 0; nt < 3; ++nt) {
        const int n = nt * 16 + col;
        bp[nt] = s_im + n * IMSTRIDE + quad * 16;
        zv[nt] = (n < 36);
        const int slz = n / 9, pos = n - slz * 9;
        zwp[nt] = s_z2 + slz * 576 + (wave * 16 + quad * 4) * 9 + pos;
    }

    float v2[12], i2[12];
    #pragma unroll
    for (int p = 0; p < 12; ++p) { v2[p] = 0.f; i2[p] = 0.f; }
    float v3a = 0.f, i3a = 0.f, v3b = 0.f, i3b = 0.f, sum0 = 0.f, sum1 = 0.f;

    const int sG = blockIdx.x * 4 + wave;
    float* outv = out + (size_t)2 * B;

    // Phase C for step tp (reads s_z2[tp&1], updates LIF3 state, stores v3_seq)
    auto do_fc = [&](int tp) {
        const float* zs = s_z2 + (tp & 1) * 2304 + wave * 576;
        float p0 = 0.f, p1 = 0.f;
        #pragma unroll
        for (int q = 0; q < 9; ++q) {
            const float z = zs[lane + 64 * q];
            p0 = fmaf(z, wf0[q], p0);
            p1 = fmaf(z, wf1[q], p1);
        }
        #pragma unroll
        for (int off = 32; off > 0; off >>= 1) {
            p0 += __shfl_xor(p0, off);
            p1 += __shfl_xor(p1, off);
        }
        const float c3a = p0 + bfv0, c3b = p1 + bfv1;
        const float vd0 = v3a + 0.1f * (i3a - v3a);
        const float vd1 = v3b + 0.1f * (i3b - v3b);
        i3a = i3a * 0.8f + c3a;
        i3b = i3b * 0.8f + c3b;
        const bool q0 = vd0 > 1.0f, q1 = vd1 > 1.0f;
        v3a = q0 ? 0.0f : vd0;
        v3b = q1 ? 0.0f : vd1;
        sum0 += q0 ? 1.0f : 0.0f;
        sum1 += q1 ? 1.0f : 0.0f;
        if (lane == 0)
            *(float2*)(outv + (size_t)tp * 2 * B + 2 * sG) = make_float2(v3a, v3b);
    };

    __syncthreads();   // x-scratch reads done before first z2 write (t=0 Phase B2)

    #pragma unroll 1
    for (int t = 0; t < NSTEPS; ++t) {
        const int zo  = (t & 1) * ZIMG;     // zimg parity offset (bytes)
        const int z2o = (t & 1) * 2304;     // z2 parity offset (floats)

        // ---- Phase A: LIF1 + im2col scatter into zimg[t&1] ----
        lif1_row(v1a, i1a, cur1a, s_im + zo, sA, icA, yA);
        if (tid < 56) lif1_row(v1b, i1b, cur1b, s_im + zo, sB, icB, yB);
        __syncthreads();                     // the only barrier per step

        // ---- Phase C (deferred): fc + LIF3 for step t-1; overlaps B's loads ----
        if (t) do_fc(t - 1);

        // ---- Phase B: MFMA from zimg[t&1], 3 interleaved acc chains ----
        f32x4 c0 = {0.f, 0.f, 0.f, 0.f}, c1 = c0, c2 = c0;
        #pragma unroll
        for (int kt = 0; kt < 7; ++kt) {
            const bf16x8 b0  = *(const bf16x8*)(bp[0] + zo + kt * 64);
            const bf16x8 b1v = *(const bf16x8*)(bp[1] + zo + kt * 64);
            const bf16x8 b2v = *(const bf16x8*)(bp[2] + zo + kt * 64);
            c0 = __builtin_amdgcn_mfma_f32_16x16x32_bf16(Alo[kt],  b0,  c0, 0, 0, 0);
            c1 = __builtin_amdgcn_mfma_f32_16x16x32_bf16(Alo[kt],  b1v, c1, 0, 0, 0);
            c2 = __builtin_amdgcn_mfma_f32_16x16x32_bf16(Alo[kt],  b2v, c2, 0, 0, 0);
            c0 = __builtin_amdgcn_mfma_f32_16x16x32_bf16(Amid[kt], b0,  c0, 0, 0, 0);
            c1 = __builtin_amdgcn_mfma_f32_16x16x32_bf16(Amid[kt], b1v, c1, 0, 0, 0);
            c2 = __builtin_amdgcn_mfma_f32_16x16x32_bf16(Amid[kt], b2v, c2, 0, 0, 0);
            c0 = __builtin_amdgcn_mfma_f32_16x16x32_bf16(Ahi[kt],  b0,  c0, 0, 0, 0);
            c1 = __builtin_amdgcn_mfma_f32_16x16x32_bf16(Ahi[kt],  b1v, c1, 0, 0, 0);
            c2 = __builtin_amdgcn_mfma_f32_16x16x32_bf16(Ahi[kt],  b2v, c2, 0, 0, 0);
        }

        // ---- Phase B2: LIF2 + z2 export into s_z2[t&1] ----
        f32x4 cc[3] = {c0, c1, c2};
        #pragma unroll
        for (int nt = 0; nt < 3; ++nt) {
            #pragma unroll
            for (int r = 0; r < 4; ++r) {
                const int p = nt * 4 + r;
                const float cur2 = cc[nt][r] + b2r[r];
                const float vd = v2[p] + 0.1f * (i2[p] - v2[p]);
                i2[p] = i2[p] * 0.8f + cur2;
                const bool sp = vd > 1.0f;
                v2[p] = sp ? 0.0f : vd;
                if (zv[nt]) zwp[nt][z2o + 9 * r] = sp ? 1.0f : 0.0f;
            }
        }
    }

    __syncthreads();
    do_fc(NSTEPS - 1);

    if (lane == 0)
        *(float2*)(out + (size_t)2 * sG) = make_float2(sum0, sum1);
}

extern "C" void kernel_launch(void* const* d_in, const int* in_sizes, int n_in,
                              void* d_out, int out_size, void* d_ws, size_t ws_size,
                              hipStream_t stream)
{
    const float* x  = (const float*)d_in[0];
    const float* w1 = (const float*)d_in[1];
    const float* b1 = (const float*)d_in[2];
    const float* w2 = (const float*)d_in[3];
    const float* b2 = (const float*)d_in[4];
    const float* wf = (const float*)d_in[5];
    const float* bf = (const float*)d_in[6];
    float* out = (float*)d_out;

    const int B = in_sizes[0] / 256;     // x is [B,1,16,16]
    const int grid = B / 4;              // 4 samples per block

    hipLaunchKernelGGL(snn_kernel, dim3(grid), dim3(256), 0, stream,
                       x, w1, b1, w2, b2, wf, bf, out, B);
}

// Round 6
// 301.421 us; speedup vs baseline: 1.3514x; 1.0144x over previous
//
#include <hip/hip_runtime.h>

// R6 = R5 skeleton with the conv2 GEMM moved to i8 MFMA (16x16x64).
// Rationale: R5 profile shows the CU-shared LDS pipe saturated (~5100 of
// 6500 cyc/CU/step). i8 halves B-read bytes (12 b128 vs 21), halves the
// scatter stores (b32 vs b64), and cuts MFMA cycles 40%.
// Numerics: spikes {0,1} exact in i8; w2 quantized per-row to 3 nested i8
// levels: w ~= W1*M/127 + W2*M/127^2 + W3*M/127^3 (M = row max|w|), error
// <= M*2.4e-7 ~ fp32-grade. i8xi8 products and i32 accumulation are EXACT.
// Layouts (16x16x64 i8, by analogy with verified bf16 16x16x32 m89/m91):
//   A[m][k]: m=lane&15, k=quad*16+j (j=byte 0..15 of the int4 operand)
//   B[k][n]: n=lane&15, k=quad*16+j
//   C/D    : col=lane&15, row=quad*4+reg   (shape-determined, m121-m128)
// im2col col stride 272 B = 68 words == 4 mod 32 -> b128 reads land one
// m-group per (col+quad) mod 8 -> exactly 8 lanes/group = conflict-free.

#define NSTEPS 100
#define IMSTRIDE 272
#define ZIMG (48 * IMSTRIDE)   // 13056 B per t-parity buffer

typedef __attribute__((ext_vector_type(4))) int i32x4;

// conv1 + 2x2 maxpool for one spike-row (sample, ic, y): 6 outputs
__device__ __forceinline__ void conv1_row(const float* __restrict__ xs,
                                          const float* __restrict__ w1s,
                                          float b1v, int y, float* cur) {
    float cr[2][12];
    #pragma unroll
    for (int rr = 0; rr < 2; ++rr) {
        const int cy = 2 * y + rr;
        #pragma unroll
        for (int cx = 0; cx < 12; ++cx) {
            float a = 0.f;
            #pragma unroll
            for (int ky = 0; ky < 4; ++ky)
            #pragma unroll
            for (int kx = 0; kx < 4; ++kx)
                a = fmaf(xs[(cy + ky) * 16 + cx + kx], w1s[ky * 4 + kx], a);
            cr[rr][cx] = a + b1v;
        }
    }
    #pragma unroll
    for (int px = 0; px < 6; ++px)
        cur[px] = fmaxf(fmaxf(cr[0][2 * px], cr[0][2 * px + 1]),
                        fmaxf(cr[1][2 * px], cr[1][2 * px + 1]));
}

// LIF1 for one spike-row + scatter i8 quads into im2col columns
__device__ __forceinline__ void lif1_row(float* v1, float* i1, const float* cur,
                                         unsigned char* s_im, int sl, int ic, int y) {
    unsigned zb[6];
    #pragma unroll
    for (int xx = 0; xx < 6; ++xx) {
        const float vd = v1[xx] + 0.1f * (i1[xx] - v1[xx]);
        i1[xx] = i1[xx] * 0.8f + cur[xx];
        const bool sp = vd > 1.0f;
        v1[xx] = sp ? 0.0f : vd;
        zb[xx] = sp ? 1u : 0u;
    }
    const unsigned q0 = zb[0] | (zb[1] << 8) | (zb[2] << 16) | (zb[3] << 24);
    const unsigned q1 = zb[1] | (zb[2] << 8) | (zb[3] << 16) | (zb[4] << 24);
    const unsigned q2 = zb[2] | (zb[3] << 8) | (zb[4] << 16) | (zb[5] << 24);
    unsigned char* rowk = s_im + ic * 16;
    #pragma unroll
    for (int ky = 0; ky < 4; ++ky) {
        const int py = y - ky;
        if (0 <= py && py <= 2) {
            unsigned char* b = rowk + (sl * 9 + py * 3) * IMSTRIDE + ky * 4;
            *(unsigned*)(b) = q0;                    // px = 0
            *(unsigned*)(b + IMSTRIDE) = q1;         // px = 1
            *(unsigned*)(b + 2 * IMSTRIDE) = q2;     // px = 2
        }
    }
}

__global__ __launch_bounds__(256, 2)
void snn_kernel(const float* __restrict__ x,
                const float* __restrict__ w1,
                const float* __restrict__ b1,
                const float* __restrict__ w2,
                const float* __restrict__ b2,
                const float* __restrict__ wf,
                const float* __restrict__ bf,
                float* __restrict__ out, int B)
{
    __shared__ __align__(16) unsigned char s_im[2 * ZIMG];   // 26112 B
    __shared__ __align__(16) float s_z2[2 * 2304];           // 18432 B; buf0 also x scratch
    __shared__ __align__(16) float s_w1[13 * 16];
    __shared__ float s_b1[13];

    const int tid  = threadIdx.x;
    const int wave = tid >> 6, lane = tid & 63;
    const int quad = lane >> 4, col = lane & 15;

    // ---- stage x into s_z2[buf0] scratch; stage w1/b1; zero both im buffers ----
    ((float4*)(s_z2 + wave * 256))[lane] =
        ((const float4*)(x + (size_t)(blockIdx.x * 4 + wave) * 256))[lane];
    if (tid < 208) s_w1[tid] = w1[tid];
    if (tid < 13)  s_b1[tid] = b1[tid];
    for (int i = tid; i < 2 * ZIMG / 16; i += 256)
        ((uint4*)s_im)[i] = make_uint4(0, 0, 0, 0);
    __syncthreads();

    // ---- LIF1 row ownership: rows R = tid and tid+256 of 312 = 4*13*6 ----
    int sA, icA, yA, sB = 0, icB = 0, yB = 0;
    { const int R = tid;       sA = R / 78; int r = R - 78 * sA; icA = r / 6; yA = r - 6 * icA; }
    if (tid < 56) { const int R = tid + 256; sB = R / 78; int r = R - 78 * sB; icB = r / 6; yB = r - 6 * icB; }

    float cur1a[6], v1a[6], i1a[6], cur1b[6], v1b[6], i1b[6];
    conv1_row(s_z2 + sA * 256, s_w1 + icA * 16, s_b1[icA], yA, cur1a);
    if (tid < 56) conv1_row(s_z2 + sB * 256, s_w1 + icB * 16, s_b1[icB], yB, cur1b);
    #pragma unroll
    for (int j = 0; j < 6; ++j) { v1a[j] = i1a[j] = 0.f; v1b[j] = i1b[j] = 0.f; }

    // ---- A-fragments: per-row 3-level i8 split of w2, static in registers ----
    // Lane (quad,col) quantizes row m=col over k = kt*64 + quad*16 + [0,16).
    i32x4 A1[4], A2[4], A3[4];
    float Mrow;                  // max|w| of row (wave*16+col)
    {
        const float* wrow = w2 + (size_t)(wave * 16 + col) * 208;
        float M = 1e-20f;
        for (int k = 0; k < 208; ++k) M = fmaxf(M, fabsf(wrow[k]));
        Mrow = M;
        const float inv = 127.0f / M;
        const float q1s = M * (1.0f / 127.0f);
        const float q2s = M * (1.0f / (127.0f * 127.0f));
        #pragma unroll
        for (int kt = 0; kt < 4; ++kt) {
            i32x4 w1v = {0, 0, 0, 0}, w2v = {0, 0, 0, 0}, w3v = {0, 0, 0, 0};
            #pragma unroll
            for (int j = 0; j < 16; ++j) {
                const int k = kt * 64 + quad * 16 + j;
                const float w = (k < 208) ? wrow[k] : 0.f;
                const float b1f = rintf(w * inv);
                const float r1  = fmaf(b1f, -q1s, w);
                const float b2f = rintf(r1 * inv * 127.0f);
                const float r2  = fmaf(b2f, -q2s, r1);
                const float b3f = rintf(r2 * inv * 127.0f * 127.0f);
                const int wi = j >> 2, sh = (j & 3) * 8;
                w1v[wi] |= ((int)b1f & 0xFF) << sh;
                w2v[wi] |= ((int)b2f & 0xFF) << sh;
                w3v[wi] |= ((int)b3f & 0xFF) << sh;
            }
            A1[kt] = w1v; A2[kt] = w2v; A3[kt] = w3v;
        }
    }
    // Reconstruction scales for this thread's C rows (row = quad*4 + r):
    float sc1[4], sc2[4], sc3[4];
    #pragma unroll
    for (int r = 0; r < 4; ++r) {
        const float Mr = __shfl(Mrow, quad * 4 + r);       // lane col = quad*4+r
        sc1[r] = Mr * (1.0f / 127.0f);
        sc2[r] = Mr * (1.0f / (127.0f * 127.0f));
        sc3[r] = Mr * (1.0f / (127.0f * 127.0f * 127.0f));
    }

    // ---- static per-lane: fc weights, b2, B-frag ptrs, z2 write ptrs ----
    float wf0[9], wf1[9];
    #pragma unroll
    for (int q = 0; q < 9; ++q) { wf0[q] = wf[lane + 64 * q]; wf1[q] = wf[576 + lane + 64 * q]; }
    const float bfv0 = bf[0], bfv1 = bf[1];
    float b2r[4];
    #pragma unroll
    for (int r = 0; r < 4; ++r) b2r[r] = b2[wave * 16 + quad * 4 + r];

    const unsigned char* bp[3];
    float* zwp[3];
    bool zv[3];
    #pragma unroll
    for (int nt = 0; nt < 3; ++nt) {
        const int n = nt * 16 + col;
        bp[nt] = s_im + n * IMSTRIDE + quad * 16;
        zv[nt] = (n < 36);
        const int slz = n / 9, pos = n - slz * 9;
        zwp[nt] = s_z2 + slz * 576 + (wave * 16 + quad * 4) * 9 + pos;
    }

    float v2[12], i2[12];
    #pragma unroll
    for (int p = 0; p < 12; ++p) { v2[p] = 0.f; i2[p] = 0.f; }
    float v3a = 0.f, i3a = 0.f, v3b = 0.f, i3b = 0.f, sum0 = 0.f, sum1 = 0.f;

    const int sG = blockIdx.x * 4 + wave;
    float* outv = out + (size_t)2 * B;

    // Phase C for step tp (reads s_z2[tp&1], updates LIF3 state, stores v3_seq)
    auto do_fc = [&](int tp) {
        const float* zs = s_z2 + (tp & 1) * 2304 + wave * 576;
        float p0 = 0.f, p1 = 0.f;
        #pragma unroll
        for (int q = 0; q < 9; ++q) {
            const float z = zs[lane + 64 * q];
            p0 = fmaf(z, wf0[q], p0);
            p1 = fmaf(z, wf1[q], p1);
        }
        #pragma unroll
        for (int off = 32; off > 0; off >>= 1) {
            p0 += __shfl_xor(p0, off);
            p1 += __shfl_xor(p1, off);
        }
        const float c3a = p0 + bfv0, c3b = p1 + bfv1;
        const float vd0 = v3a + 0.1f * (i3a - v3a);
        const float vd1 = v3b + 0.1f * (i3b - v3b);
        i3a = i3a * 0.8f + c3a;
        i3b = i3b * 0.8f + c3b;
        const bool q0 = vd0 > 1.0f, q1 = vd1 > 1.0f;
        v3a = q0 ? 0.0f : vd0;
        v3b = q1 ? 0.0f : vd1;
        sum0 += q0 ? 1.0f : 0.0f;
        sum1 += q1 ? 1.0f : 0.0f;
        if (lane == 0)
            *(float2*)(outv + (size_t)tp * 2 * B + 2 * sG) = make_float2(v3a, v3b);
    };

    __syncthreads();   // x-scratch reads done before first z2 write (t=0 Phase B2)

    #pragma unroll 1
    for (int t = 0; t < NSTEPS; ++t) {
        const int zo  = (t & 1) * ZIMG;     // zimg parity offset (bytes)
        const int z2o = (t & 1) * 2304;     // z2 parity offset (floats)

        // ---- Phase A: LIF1 + i8 im2col scatter into zimg[t&1] ----
        lif1_row(v1a, i1a, cur1a, s_im + zo, sA, icA, yA);
        if (tid < 56) lif1_row(v1b, i1b, cur1b, s_im + zo, sB, icB, yB);
        __syncthreads();                     // the only barrier per step

        // ---- Phase C (deferred): fc + LIF3 for step t-1; overlaps B's loads ----
        if (t) do_fc(t - 1);

        // ---- Phase B: i8 MFMA, 9 independent acc chains (3 levels x 3 nt) ----
        i32x4 c1a = {0,0,0,0}, c1b = c1a, c1c = c1a;   // level 1
        i32x4 c2a = c1a, c2b = c1a, c2c = c1a;         // level 2
        i32x4 c3a_ = c1a, c3b_ = c1a, c3c = c1a;       // level 3
        #pragma unroll
        for (int kt = 0; kt < 4; ++kt) {
            const i32x4 B0 = *(const i32x4*)(bp[0] + zo + kt * 64);
            const i32x4 B1 = *(const i32x4*)(bp[1] + zo + kt * 64);
            const i32x4 B2 = *(const i32x4*)(bp[2] + zo + kt * 64);
            c1a = __builtin_amdgcn_mfma_i32_16x16x64_i8(A1[kt], B0, c1a, 0, 0, 0);
            c1b = __builtin_amdgcn_mfma_i32_16x16x64_i8(A1[kt], B1, c1b, 0, 0, 0);
            c1c = __builtin_amdgcn_mfma_i32_16x16x64_i8(A1[kt], B2, c1c, 0, 0, 0);
            c2a = __builtin_amdgcn_mfma_i32_16x16x64_i8(A2[kt], B0, c2a, 0, 0, 0);
            c2b = __builtin_amdgcn_mfma_i32_16x16x64_i8(A2[kt], B1, c2b, 0, 0, 0);
            c2c = __builtin_amdgcn_mfma_i32_16x16x64_i8(A2[kt], B2, c2c, 0, 0, 0);
            c3a_ = __builtin_amdgcn_mfma_i32_16x16x64_i8(A3[kt], B0, c3a_, 0, 0, 0);
            c3b_ = __builtin_amdgcn_mfma_i32_16x16x64_i8(A3[kt], B1, c3b_, 0, 0, 0);
            c3c = __builtin_amdgcn_mfma_i32_16x16x64_i8(A3[kt], B2, c3c, 0, 0, 0);
        }

        // ---- Phase B2: reconstruct cur2, LIF2, z2 export into s_z2[t&1] ----
        const i32x4 L1[3] = {c1a, c1b, c1c};
        const i32x4 L2[3] = {c2a, c2b, c2c};
        const i32x4 L3[3] = {c3a_, c3b_, c3c};
        #pragma unroll
        for (int nt = 0; nt < 3; ++nt) {
            #pragma unroll
            for (int r = 0; r < 4; ++r) {
                const int p = nt * 4 + r;
                const float cur2 =
                    fmaf(sc1[r], (float)L1[nt][r],
                    fmaf(sc2[r], (float)L2[nt][r],
                    fmaf(sc3[r], (float)L3[nt][r], b2r[r])));
                const float vd = v2[p] + 0.1f * (i2[p] - v2[p]);
                i2[p] = i2[p] * 0.8f + cur2;
                const bool sp = vd > 1.0f;
                v2[p] = sp ? 0.0f : vd;
                if (zv[nt]) zwp[nt][z2o + 9 * r] = sp ? 1.0f : 0.0f;
            }
        }
    }

    __syncthreads();
    do_fc(NSTEPS - 1);

    if (lane == 0)
        *(float2*)(out + (size_t)2 * sG) = make_float2(sum0, sum1);
}

extern "C" void kernel_launch(void* const* d_in, const int* in_sizes, int n_in,
                              void* d_out, int out_size, void* d_ws, size_t ws_size,
                              hipStream_t stream)
{
    const float* x  = (const float*)d_in[0];
    const float* w1 = (const float*)d_in[1];
    const float* b1 = (const float*)d_in[2];
    const float* w2 = (const float*)d_in[3];
    const float* b2 = (const float*)d_in[4];
    const float* wf = (const float*)d_in[5];
    const float* bf = (const float*)d_in[6];
    float* out = (float*)d_out;

    const int B = in_sizes[0] / 256;     // x is [B,1,16,16]
    const int grid = B / 4;              // 4 samples per block

    hipLaunchKernelGGL(snn_kernel, dim3(grid), dim3(256), 0, stream,
                       x, w1, b1, w2, b2, wf, bf, out, B);
}

// Round 7
// 271.296 us; speedup vs baseline: 1.5015x; 1.1110x over previous
//
#include <hip/hip_runtime.h>

// R7 = R6 skeleton + three LDS surgeries:
//  (1) sigma-permuted im2col K-layout: word(ic,ky) = 4*ic + ((ky+ic)&3).
//      Scatter bank = 4*((9sl+3py+px+ic) mod 8) + ((ky+ic)&3): the low-2-bit
//      sigma term breaks R6's 4-way scatter conflicts (only ic<->ic+8 2-way
//      aliasing remains = free). A-fragments invert the same map, so the
//      GEMM contraction is unchanged (K permutation is free when A is built
//      in-kernel).
//  (2) z2 export: layout [slz][pos(stride 68w)][64 oc] -> one float4 store
//      per nt (3 b128 vs 12 b32); fc reads z2[q*68+lane] (2-way banks) with
//      re-indexed per-lane wf (wf0[q] = wf[lane*9+q]).
//  (3) explicit 2-step parity unroll: no per-step zo/z2o pointer arithmetic.
// Numerics identical to R6: 3-level nested i8 (error ~M*2.4e-7), spikes
// exact in i8, i32 accumulation exact.

#define NSTEPS 100
#define IMSTRIDE 272
#define ZIMG (48 * IMSTRIDE)   // 13056 B per t-parity buffer
#define Z2W 612                // z2 words per sample (9 pos * 68)
#define Z2P (4 * Z2W)          // z2 words per parity

typedef __attribute__((ext_vector_type(4))) int i32x4;

// conv1 + 2x2 maxpool for one spike-row (sample, ic, y): 6 outputs
__device__ __forceinline__ void conv1_row(const float* __restrict__ xs,
                                          const float* __restrict__ w1s,
                                          float b1v, int y, float* cur) {
    float cr[2][12];
    #pragma unroll
    for (int rr = 0; rr < 2; ++rr) {
        const int cy = 2 * y + rr;
        #pragma unroll
        for (int cx = 0; cx < 12; ++cx) {
            float a = 0.f;
            #pragma unroll
            for (int ky = 0; ky < 4; ++ky)
            #pragma unroll
            for (int kx = 0; kx < 4; ++kx)
                a = fmaf(xs[(cy + ky) * 16 + cx + kx], w1s[ky * 4 + kx], a);
            cr[rr][cx] = a + b1v;
        }
    }
    #pragma unroll
    for (int px = 0; px < 6; ++px)
        cur[px] = fmaxf(fmaxf(cr[0][2 * px], cr[0][2 * px + 1]),
                        fmaxf(cr[1][2 * px], cr[1][2 * px + 1]));
}

// LIF1 for one spike-row + sigma-permuted i8 scatter.
// pb = zimg_parity_base + (9*sl + 3*y)*IMSTRIDE + 16*ic
__device__ __forceinline__ void lif1_row(float* v1, float* i1, const float* cur,
                                         unsigned char* pb, int ic, int y) {
    unsigned zb[6];
    #pragma unroll
    for (int xx = 0; xx < 6; ++xx) {
        const float vd = v1[xx] + 0.1f * (i1[xx] - v1[xx]);
        i1[xx] = i1[xx] * 0.8f + cur[xx];
        const bool sp = vd > 1.0f;
        v1[xx] = sp ? 0.0f : vd;
        zb[xx] = sp ? 1u : 0u;
    }
    const unsigned q0 = zb[0] | (zb[1] << 8) | (zb[2] << 16) | (zb[3] << 24);
    const unsigned q1 = zb[1] | (zb[2] << 8) | (zb[3] << 16) | (zb[4] << 24);
    const unsigned q2 = zb[2] | (zb[3] << 8) | (zb[4] << 16) | (zb[5] << 24);
    #pragma unroll
    for (int ky = 0; ky < 4; ++ky) {
        const int py = y - ky;
        if (0 <= py && py <= 2) {
            // column c0 = 9sl+3py: pb - ky*3*IMSTRIDE; word sigma = (ky+ic)&3
            unsigned char* b = pb - ky * (3 * IMSTRIDE) + 4 * ((ky + ic) & 3);
            *(unsigned*)(b)                = q0;   // px = 0
            *(unsigned*)(b + IMSTRIDE)     = q1;   // px = 1
            *(unsigned*)(b + 2 * IMSTRIDE) = q2;   // px = 2
        }
    }
}

__global__ __launch_bounds__(256, 2)
void snn_kernel(const float* __restrict__ x,
                const float* __restrict__ w1,
                const float* __restrict__ b1,
                const float* __restrict__ w2,
                const float* __restrict__ b2,
                const float* __restrict__ wf,
                const float* __restrict__ bf,
                float* __restrict__ out, int B)
{
    __shared__ __align__(16) unsigned char s_im[2 * ZIMG];   // 26112 B
    __shared__ __align__(16) float s_z2[2 * Z2P];            // 19584 B; also x scratch
    __shared__ __align__(16) float s_w1[13 * 16];
    __shared__ float s_b1[13];

    const int tid  = threadIdx.x;
    const int wave = tid >> 6, lane = tid & 63;
    const int quad = lane >> 4, col = lane & 15;

    // ---- stage x into s_z2 scratch; stage w1/b1; zero both im buffers ----
    ((float4*)(s_z2 + wave * Z2W))[lane] =
        ((const float4*)(x + (size_t)(blockIdx.x * 4 + wave) * 256))[lane];
    if (tid < 208) s_w1[tid] = w1[tid];
    if (tid < 13)  s_b1[tid] = b1[tid];
    for (int i = tid; i < 2 * ZIMG / 16; i += 256)
        ((uint4*)s_im)[i] = make_uint4(0, 0, 0, 0);
    __syncthreads();

    // ---- LIF1 row ownership: rows R = tid and tid+256 of 312 = 4*13*6 ----
    int sA, icA, yA, sB = 0, icB = 0, yB = 0;
    { const int R = tid;       sA = R / 78; int r = R - 78 * sA; icA = r / 6; yA = r - 6 * icA; }
    if (tid < 56) { const int R = tid + 256; sB = R / 78; int r = R - 78 * sB; icB = r / 6; yB = r - 6 * icB; }

    float cur1a[6], v1a[6], i1a[6], cur1b[6], v1b[6], i1b[6];
    conv1_row(s_z2 + sA * Z2W, s_w1 + icA * 16, s_b1[icA], yA, cur1a);
    if (tid < 56) conv1_row(s_z2 + sB * Z2W, s_w1 + icB * 16, s_b1[icB], yB, cur1b);
    #pragma unroll
    for (int j = 0; j < 6; ++j) { v1a[j] = i1a[j] = 0.f; v1b[j] = i1b[j] = 0.f; }

    const int pbOffA = (9 * sA + 3 * yA) * IMSTRIDE + 16 * icA;
    const int pbOffB = (9 * sB + 3 * yB) * IMSTRIDE + 16 * icB;

    // ---- A-fragments: per-row 3-level i8 split of w2 (sigma-permuted K) ----
    i32x4 A1[4], A2[4], A3[4];
    float Mrow;
    {
        const float* wrow = w2 + (size_t)(wave * 16 + col) * 208;
        float M = 1e-20f;
        for (int k = 0; k < 208; ++k) M = fmaxf(M, fabsf(wrow[k]));
        Mrow = M;
        const float inv = 127.0f / M;
        const float q1s = M * (1.0f / 127.0f);
        const float q2s = M * (1.0f / (127.0f * 127.0f));
        #pragma unroll
        for (int kt = 0; kt < 4; ++kt) {
            i32x4 w1v = {0, 0, 0, 0}, w2v = {0, 0, 0, 0}, w3v = {0, 0, 0, 0};
            #pragma unroll
            for (int j = 0; j < 16; ++j) {
                const int kp = kt * 64 + quad * 16 + j;     // physical k byte
                const int W = kp >> 2, kx = kp & 3;
                const int ic = W >> 2, ky = ((W & 3) - ic) & 3;
                const float w = (ic < 13) ? wrow[ic * 16 + ky * 4 + kx] : 0.f;
                const float b1f = rintf(w * inv);
                const float r1  = fmaf(b1f, -q1s, w);
                const float b2f = rintf(r1 * inv * 127.0f);
                const float r2  = fmaf(b2f, -q2s, r1);
                const float b3f = rintf(r2 * inv * 127.0f * 127.0f);
                const int wi = j >> 2, sh = (j & 3) * 8;
                w1v[wi] |= ((int)b1f & 0xFF) << sh;
                w2v[wi] |= ((int)b2f & 0xFF) << sh;
                w3v[wi] |= ((int)b3f & 0xFF) << sh;
            }
            A1[kt] = w1v; A2[kt] = w2v; A3[kt] = w3v;
        }
    }
    float sc1[4], sc2[4], sc3[4];
    #pragma unroll
    for (int r = 0; r < 4; ++r) {
        const float Mr = __shfl(Mrow, quad * 4 + r);
        sc1[r] = Mr * (1.0f / 127.0f);
        sc2[r] = Mr * (1.0f / (127.0f * 127.0f));
        sc3[r] = Mr * (1.0f / (127.0f * 127.0f * 127.0f));
    }

    // ---- static per-lane: fc weights (new z2 layout), b2, ptr offsets ----
    float wf0[9], wf1[9];
    #pragma unroll
    for (int q = 0; q < 9; ++q) {
        wf0[q] = wf[lane * 9 + q];          // z2 read (pos=q, oc=lane)
        wf1[q] = wf[576 + lane * 9 + q];
    }
    const float bfv0 = bf[0], bfv1 = bf[1];
    float b2r[4];
    #pragma unroll
    for (int r = 0; r < 4; ++r) b2r[r] = b2[wave * 16 + quad * 4 + r];

    const unsigned char* bp[3];
    int zoff[3];
    bool zv[3];
    #pragma unroll
    for (int nt = 0; nt < 3; ++nt) {
        const int n = nt * 16 + col;
        bp[nt] = s_im + n * IMSTRIDE + quad * 16;
        zv[nt] = (n < 36);
        const int slz = n / 9, pos = n - slz * 9;
        zoff[nt] = slz * Z2W + pos * 68 + wave * 16 + quad * 4;
    }

    float v2[12], i2[12];
    #pragma unroll
    for (int p = 0; p < 12; ++p) { v2[p] = 0.f; i2[p] = 0.f; }
    float v3a = 0.f, i3a = 0.f, v3b = 0.f, i3b = 0.f, sum0 = 0.f, sum1 = 0.f;

    const int sG = blockIdx.x * 4 + wave;
    float* outv = out + (size_t)2 * B;

    auto do_fc = [&](int tp) {
        const float* zs = s_z2 + (tp & 1) * Z2P + wave * Z2W;
        float p0 = 0.f, p1 = 0.f;
        #pragma unroll
        for (int q = 0; q < 9; ++q) {
            const float z = zs[q * 68 + lane];
            p0 = fmaf(z, wf0[q], p0);
            p1 = fmaf(z, wf1[q], p1);
        }
        #pragma unroll
        for (int off = 32; off > 0; off >>= 1) {
            p0 += __shfl_xor(p0, off);
            p1 += __shfl_xor(p1, off);
        }
        const float c3a = p0 + bfv0, c3b = p1 + bfv1;
        const float vd0 = v3a + 0.1f * (i3a - v3a);
        const float vd1 = v3b + 0.1f * (i3b - v3b);
        i3a = i3a * 0.8f + c3a;
        i3b = i3b * 0.8f + c3b;
        const bool q0 = vd0 > 1.0f, q1 = vd1 > 1.0f;
        v3a = q0 ? 0.0f : vd0;
        v3b = q1 ? 0.0f : vd1;
        sum0 += q0 ? 1.0f : 0.0f;
        sum1 += q1 ? 1.0f : 0.0f;
        if (lane == 0)
            *(float2*)(outv + (size_t)tp * 2 * B + 2 * sG) = make_float2(v3a, v3b);
    };

    // One timestep with compile-time parity P.
    auto step = [&](int t, int P) {
        unsigned char* zb = s_im + P * ZIMG;
        lif1_row(v1a, i1a, cur1a, zb + pbOffA, icA, yA);
        if (tid < 56) lif1_row(v1b, i1b, cur1b, zb + pbOffB, icB, yB);
        __syncthreads();

        if (t) do_fc(t - 1);   // overlaps B's LDS loads

        i32x4 c1a = {0,0,0,0}, c1b = c1a, c1c = c1a;
        i32x4 c2a = c1a, c2b = c1a, c2c = c1a;
        i32x4 c3a_ = c1a, c3b_ = c1a, c3c = c1a;
        const int zo = P * ZIMG;
        #pragma unroll
        for (int kt = 0; kt < 4; ++kt) {
            const i32x4 B0 = *(const i32x4*)(bp[0] + zo + kt * 64);
            const i32x4 B1 = *(const i32x4*)(bp[1] + zo + kt * 64);
            const i32x4 B2 = *(const i32x4*)(bp[2] + zo + kt * 64);
            c1a = __builtin_amdgcn_mfma_i32_16x16x64_i8(A1[kt], B0, c1a, 0, 0, 0);
            c1b = __builtin_amdgcn_mfma_i32_16x16x64_i8(A1[kt], B1, c1b, 0, 0, 0);
            c1c = __builtin_amdgcn_mfma_i32_16x16x64_i8(A1[kt], B2, c1c, 0, 0, 0);
            c2a = __builtin_amdgcn_mfma_i32_16x16x64_i8(A2[kt], B0, c2a, 0, 0, 0);
            c2b = __builtin_amdgcn_mfma_i32_16x16x64_i8(A2[kt], B1, c2b, 0, 0, 0);
            c2c = __builtin_amdgcn_mfma_i32_16x16x64_i8(A2[kt], B2, c2c, 0, 0, 0);
            c3a_ = __builtin_amdgcn_mfma_i32_16x16x64_i8(A3[kt], B0, c3a_, 0, 0, 0);
            c3b_ = __builtin_amdgcn_mfma_i32_16x16x64_i8(A3[kt], B1, c3b_, 0, 0, 0);
            c3c = __builtin_amdgcn_mfma_i32_16x16x64_i8(A3[kt], B2, c3c, 0, 0, 0);
        }

        const i32x4 L1[3] = {c1a, c1b, c1c};
        const i32x4 L2[3] = {c2a, c2b, c2c};
        const i32x4 L3[3] = {c3a_, c3b_, c3c};
        float* z2p = s_z2 + P * Z2P;
        #pragma unroll
        for (int nt = 0; nt < 3; ++nt) {
            float4 zq;
            float* zqf = (float*)&zq;
            #pragma unroll
            for (int r = 0; r < 4; ++r) {
                const int p = nt * 4 + r;
                const float cur2 =
                    fmaf(sc1[r], (float)L1[nt][r],
                    fmaf(sc2[r], (float)L2[nt][r],
                    fmaf(sc3[r], (float)L3[nt][r], b2r[r])));
                const float vd = v2[p] + 0.1f * (i2[p] - v2[p]);
                i2[p] = i2[p] * 0.8f + cur2;
                const bool sp = vd > 1.0f;
                v2[p] = sp ? 0.0f : vd;
                zqf[r] = sp ? 1.0f : 0.0f;
            }
            if (zv[nt]) *(float4*)(z2p + zoff[nt]) = zq;
        }
    };

    __syncthreads();   // x-scratch reads complete before first z2 write

    #pragma unroll 1
    for (int t = 0; t < NSTEPS; t += 2) {
        step(t, 0);
        step(t + 1, 1);
    }

    __syncthreads();
    do_fc(NSTEPS - 1);

    if (lane == 0)
        *(float2*)(out + (size_t)2 * sG) = make_float2(sum0, sum1);
}

extern "C" void kernel_launch(void* const* d_in, const int* in_sizes, int n_in,
                              void* d_out, int out_size, void* d_ws, size_t ws_size,
                              hipStream_t stream)
{
    const float* x  = (const float*)d_in[0];
    const float* w1 = (const float*)d_in[1];
    const float* b1 = (const float*)d_in[2];
    const float* w2 = (const float*)d_in[3];
    const float* b2 = (const float*)d_in[4];
    const float* wf = (const float*)d_in[5];
    const float* bf = (const float*)d_in[6];
    float* out = (float*)d_out;

    const int B = in_sizes[0] / 256;     // x is [B,1,16,16]
    const int grid = B / 4;              // 4 samples per block

    hipLaunchKernelGGL(snn_kernel, dim3(grid), dim3(256), 0, stream,
                       x, w1, b1, w2, b2, wf, bf, out, B);
}

// Round 8
// 270.489 us; speedup vs baseline: 1.5060x; 1.0030x over previous
//
#include <hip/hip_runtime.h>

// R8 = R7 + Tc=2 time chunking (1 barrier per 2 steps) + bf16 z2.
//  - 4 z-image buffers (chunk parity x t-in-chunk): one __syncthreads per
//    chunk is hazard-free (writers/readers separated by >=1 barrier).
//  - deferred fc handles BOTH steps of the previous chunk back-to-back:
//    the 4 butterfly reduction chains interleave -> latency halves/step.
//  - z2 spike buffer in bf16 (spikes {0,1} exact): 4 zimg + 2 z2 parities
//    fit in ~75 KB LDS -> still 2 blocks/CU.
//  - GEMM = two serial 9-chain passes (acc stays 36 VGPRs; pass-2 B-loads
//    prefetch under pass-1 MFMAs).
// Numerics identical to R7: 3-level nested i8 (~fp32-grade), exact i32 acc.

#define NSTEPS 100
#define NCHUNK 50
#define IMSTRIDE 272
#define ZIMG (48 * IMSTRIDE)   // 13056 B per buffer; 4 buffers
#define Z2S 612                // shorts per (sample, step); 68-short pos stride
#define Z2T (4 * Z2S)          // shorts per t-slot
#define Z2PAR (2 * Z2T)        // shorts per chunk parity

typedef __attribute__((ext_vector_type(4))) int i32x4;

// conv1 + 2x2 maxpool for one spike-row (sample, ic, y): 6 outputs
__device__ __forceinline__ void conv1_row(const float* __restrict__ xs,
                                          const float* __restrict__ w1s,
                                          float b1v, int y, float* cur) {
    float cr[2][12];
    #pragma unroll
    for (int rr = 0; rr < 2; ++rr) {
        const int cy = 2 * y + rr;
        #pragma unroll
        for (int cx = 0; cx < 12; ++cx) {
            float a = 0.f;
            #pragma unroll
            for (int ky = 0; ky < 4; ++ky)
            #pragma unroll
            for (int kx = 0; kx < 4; ++kx)
                a = fmaf(xs[(cy + ky) * 16 + cx + kx], w1s[ky * 4 + kx], a);
            cr[rr][cx] = a + b1v;
        }
    }
    #pragma unroll
    for (int px = 0; px < 6; ++px)
        cur[px] = fmaxf(fmaxf(cr[0][2 * px], cr[0][2 * px + 1]),
                        fmaxf(cr[1][2 * px], cr[1][2 * px + 1]));
}

// LIF1 step for one spike-row + sigma-permuted i8 scatter (R7 layout).
// pb = zimg_buffer_base + (9*sl + 3*y)*IMSTRIDE + 16*ic
__device__ __forceinline__ void lif1_row(float* v1, float* i1, const float* cur,
                                         unsigned char* pb, int ic, int y) {
    unsigned zb[6];
    #pragma unroll
    for (int xx = 0; xx < 6; ++xx) {
        const float vd = v1[xx] + 0.1f * (i1[xx] - v1[xx]);
        i1[xx] = i1[xx] * 0.8f + cur[xx];
        const bool sp = vd > 1.0f;
        v1[xx] = sp ? 0.0f : vd;
        zb[xx] = sp ? 1u : 0u;
    }
    const unsigned q0 = zb[0] | (zb[1] << 8) | (zb[2] << 16) | (zb[3] << 24);
    const unsigned q1 = zb[1] | (zb[2] << 8) | (zb[3] << 16) | (zb[4] << 24);
    const unsigned q2 = zb[2] | (zb[3] << 8) | (zb[4] << 16) | (zb[5] << 24);
    #pragma unroll
    for (int ky = 0; ky < 4; ++ky) {
        const int py = y - ky;
        if (0 <= py && py <= 2) {
            unsigned char* b = pb - ky * (3 * IMSTRIDE) + 4 * ((ky + ic) & 3);
            *(unsigned*)(b)                = q0;   // px = 0
            *(unsigned*)(b + IMSTRIDE)     = q1;   // px = 1
            *(unsigned*)(b + 2 * IMSTRIDE) = q2;   // px = 2
        }
    }
}

__global__ __launch_bounds__(256, 2)
void snn_kernel(const float* __restrict__ x,
                const float* __restrict__ w1,
                const float* __restrict__ b1,
                const float* __restrict__ w2,
                const float* __restrict__ b2,
                const float* __restrict__ wf,
                const float* __restrict__ bf,
                float* __restrict__ out, int B)
{
    __shared__ __align__(16) unsigned char s_im[4 * ZIMG];       // 52224 B
    __shared__ __align__(16) unsigned short s_z2h[2 * Z2PAR];    // 19584 B
    __shared__ __align__(16) float s_x[4 * 256];                 // 4096 B
    __shared__ __align__(16) float s_w1[13 * 16];
    __shared__ float s_b1[13];

    const int tid  = threadIdx.x;
    const int wave = tid >> 6, lane = tid & 63;
    const int quad = lane >> 4, col = lane & 15;

    // ---- stage x / w1 / b1; zero all 4 zimg buffers ----
    ((float4*)(s_x + wave * 256))[lane] =
        ((const float4*)(x + (size_t)(blockIdx.x * 4 + wave) * 256))[lane];
    if (tid < 208) s_w1[tid] = w1[tid];
    if (tid < 13)  s_b1[tid] = b1[tid];
    for (int i = tid; i < 4 * ZIMG / 16; i += 256)
        ((uint4*)s_im)[i] = make_uint4(0, 0, 0, 0);
    __syncthreads();

    // ---- LIF1 row ownership: rows R = tid and tid+256 of 312 = 4*13*6 ----
    int sA, icA, yA, sB = 0, icB = 0, yB = 0;
    { const int R = tid;       sA = R / 78; int r = R - 78 * sA; icA = r / 6; yA = r - 6 * icA; }
    if (tid < 56) { const int R = tid + 256; sB = R / 78; int r = R - 78 * sB; icB = r / 6; yB = r - 6 * icB; }

    float cur1a[6], v1a[6], i1a[6], cur1b[6], v1b[6], i1b[6];
    conv1_row(s_x + sA * 256, s_w1 + icA * 16, s_b1[icA], yA, cur1a);
    if (tid < 56) conv1_row(s_x + sB * 256, s_w1 + icB * 16, s_b1[icB], yB, cur1b);
    #pragma unroll
    for (int j = 0; j < 6; ++j) { v1a[j] = i1a[j] = 0.f; v1b[j] = i1b[j] = 0.f; }

    const int pbOffA = (9 * sA + 3 * yA) * IMSTRIDE + 16 * icA;
    const int pbOffB = (9 * sB + 3 * yB) * IMSTRIDE + 16 * icB;

    // ---- A-fragments: per-row 3-level i8 split of w2 (sigma-permuted K) ----
    i32x4 A1[4], A2[4], A3[4];
    float Mrow;
    {
        const float* wrow = w2 + (size_t)(wave * 16 + col) * 208;
        float M = 1e-20f;
        for (int k = 0; k < 208; ++k) M = fmaxf(M, fabsf(wrow[k]));
        Mrow = M;
        const float inv = 127.0f / M;
        const float q1s = M * (1.0f / 127.0f);
        const float q2s = M * (1.0f / (127.0f * 127.0f));
        #pragma unroll
        for (int kt = 0; kt < 4; ++kt) {
            i32x4 w1v = {0, 0, 0, 0}, w2v = {0, 0, 0, 0}, w3v = {0, 0, 0, 0};
            #pragma unroll
            for (int j = 0; j < 16; ++j) {
                const int kp = kt * 64 + quad * 16 + j;
                const int W = kp >> 2, kx = kp & 3;
                const int ic = W >> 2, ky = ((W & 3) - ic) & 3;
                const float w = (ic < 13) ? wrow[ic * 16 + ky * 4 + kx] : 0.f;
                const float b1f = rintf(w * inv);
                const float r1  = fmaf(b1f, -q1s, w);
                const float b2f = rintf(r1 * inv * 127.0f);
                const float r2  = fmaf(b2f, -q2s, r1);
                const float b3f = rintf(r2 * inv * 127.0f * 127.0f);
                const int wi = j >> 2, sh = (j & 3) * 8;
                w1v[wi] |= ((int)b1f & 0xFF) << sh;
                w2v[wi] |= ((int)b2f & 0xFF) << sh;
                w3v[wi] |= ((int)b3f & 0xFF) << sh;
            }
            A1[kt] = w1v; A2[kt] = w2v; A3[kt] = w3v;
        }
    }
    float sc1[4], sc2[4], sc3[4];
    #pragma unroll
    for (int r = 0; r < 4; ++r) {
        const float Mr = __shfl(Mrow, quad * 4 + r);
        sc1[r] = Mr * (1.0f / 127.0f);
        sc2[r] = Mr * (1.0f / (127.0f * 127.0f));
        sc3[r] = Mr * (1.0f / (127.0f * 127.0f * 127.0f));
    }

    // ---- static per-lane: fc weights, b2, B-frag / z2 offsets ----
    float wf0[9], wf1[9];
    #pragma unroll
    for (int q = 0; q < 9; ++q) {
        wf0[q] = wf[lane * 9 + q];          // fc reads z2h[q*68 + lane] (oc=lane)
        wf1[q] = wf[576 + lane * 9 + q];
    }
    const float bfv0 = bf[0], bfv1 = bf[1];
    float b2r[4];
    #pragma unroll
    for (int r = 0; r < 4; ++r) b2r[r] = b2[wave * 16 + quad * 4 + r];

    int bpo[3];        // byte offset of B-frag within a zimg buffer
    int zwo[3];        // short offset of z2 write within a t-slot
    bool zv[3];
    #pragma unroll
    for (int nt = 0; nt < 3; ++nt) {
        const int n = nt * 16 + col;
        bpo[nt] = n * IMSTRIDE + quad * 16;
        zv[nt] = (n < 36);
        const int slz = n / 9, pos = n - slz * 9;
        zwo[nt] = slz * Z2S + pos * 68 + wave * 16 + quad * 4;
    }

    float v2[12], i2[12];
    #pragma unroll
    for (int p = 0; p < 12; ++p) { v2[p] = 0.f; i2[p] = 0.f; }
    float v3a = 0.f, i3a = 0.f, v3b = 0.f, i3b = 0.f, sum0 = 0.f, sum1 = 0.f;

    const int sG = blockIdx.x * 4 + wave;
    float* outv = out + (size_t)2 * B;

    // One fc + LIF3 step from a z2h t-slot base (shorts), storing v3_seq[tp].
    auto fc_step = [&](const unsigned short* zs, int tp) {
        float p0 = 0.f, p1 = 0.f;
        #pragma unroll
        for (int q = 0; q < 9; ++q) {
            const float z = __uint_as_float(((unsigned)zs[q * 68 + lane]) << 16);
            p0 = fmaf(z, wf0[q], p0);
            p1 = fmaf(z, wf1[q], p1);
        }
        #pragma unroll
        for (int off = 32; off > 0; off >>= 1) {
            p0 += __shfl_xor(p0, off);
            p1 += __shfl_xor(p1, off);
        }
        const float c3a = p0 + bfv0, c3b = p1 + bfv1;
        const float vd0 = v3a + 0.1f * (i3a - v3a);
        const float vd1 = v3b + 0.1f * (i3b - v3b);
        i3a = i3a * 0.8f + c3a;
        i3b = i3b * 0.8f + c3b;
        const bool q0 = vd0 > 1.0f, q1 = vd1 > 1.0f;
        v3a = q0 ? 0.0f : vd0;
        v3b = q1 ? 0.0f : vd1;
        sum0 += q0 ? 1.0f : 0.0f;
        sum1 += q1 ? 1.0f : 0.0f;
        if (lane == 0)
            *(float2*)(outv + (size_t)tp * 2 * B + 2 * sG) = make_float2(v3a, v3b);
    };

    // One chunk (2 timesteps), compile-time parity P at call sites.
    auto chunk = [&](int ch, int P) {
        // ---- Phase A: two LIF1 steps into zimg buffers 2P, 2P+1 ----
        unsigned char* zb0 = s_im + (2 * P) * ZIMG;
        unsigned char* zb1 = s_im + (2 * P + 1) * ZIMG;
        lif1_row(v1a, i1a, cur1a, zb0 + pbOffA, icA, yA);
        if (tid < 56) lif1_row(v1b, i1b, cur1b, zb0 + pbOffB, icB, yB);
        lif1_row(v1a, i1a, cur1a, zb1 + pbOffA, icA, yA);
        if (tid < 56) lif1_row(v1b, i1b, cur1b, zb1 + pbOffB, icB, yB);
        __syncthreads();                 // the only barrier per 2 steps

        // ---- deferred fc: both steps of chunk ch-1 (parity !P) ----
        if (ch) {
            const unsigned short* zp = s_z2h + (P ^ 1) * Z2PAR + wave * Z2S;
            fc_step(zp, 2 * ch - 2);
            fc_step(zp + Z2T, 2 * ch - 1);
        }

        // ---- GEMM + LIF2: two serial 9-chain passes ----
        #pragma unroll
        for (int tl = 0; tl < 2; ++tl) {
            const unsigned char* zbuf = s_im + (2 * P + tl) * ZIMG;
            i32x4 c1a = {0,0,0,0}, c1b = c1a, c1c = c1a;
            i32x4 c2a = c1a, c2b = c1a, c2c = c1a;
            i32x4 c3a_ = c1a, c3b_ = c1a, c3c = c1a;
            #pragma unroll
            for (int kt = 0; kt < 4; ++kt) {
                const i32x4 B0 = *(const i32x4*)(zbuf + bpo[0] + kt * 64);
                const i32x4 B1 = *(const i32x4*)(zbuf + bpo[1] + kt * 64);
                const i32x4 B2v = *(const i32x4*)(zbuf + bpo[2] + kt * 64);
                c1a = __builtin_amdgcn_mfma_i32_16x16x64_i8(A1[kt], B0,  c1a, 0, 0, 0);
                c1b = __builtin_amdgcn_mfma_i32_16x16x64_i8(A1[kt], B1,  c1b, 0, 0, 0);
                c1c = __builtin_amdgcn_mfma_i32_16x16x64_i8(A1[kt], B2v, c1c, 0, 0, 0);
                c2a = __builtin_amdgcn_mfma_i32_16x16x64_i8(A2[kt], B0,  c2a, 0, 0, 0);
                c2b = __builtin_amdgcn_mfma_i32_16x16x64_i8(A2[kt], B1,  c2b, 0, 0, 0);
                c2c = __builtin_amdgcn_mfma_i32_16x16x64_i8(A2[kt], B2v, c2c, 0, 0, 0);
                c3a_ = __builtin_amdgcn_mfma_i32_16x16x64_i8(A3[kt], B0,  c3a_, 0, 0, 0);
                c3b_ = __builtin_amdgcn_mfma_i32_16x16x64_i8(A3[kt], B1,  c3b_, 0, 0, 0);
                c3c = __builtin_amdgcn_mfma_i32_16x16x64_i8(A3[kt], B2v, c3c, 0, 0, 0);
            }

            const i32x4 L1[3] = {c1a, c1b, c1c};
            const i32x4 L2[3] = {c2a, c2b, c2c};
            const i32x4 L3[3] = {c3a_, c3b_, c3c};
            unsigned short* z2b = s_z2h + P * Z2PAR + tl * Z2T;
            #pragma unroll
            for (int nt = 0; nt < 3; ++nt) {
                unsigned zbits[4];
                #pragma unroll
                for (int r = 0; r < 4; ++r) {
                    const int p = nt * 4 + r;
                    const float cur2 =
                        fmaf(sc1[r], (float)L1[nt][r],
                        fmaf(sc2[r], (float)L2[nt][r],
                        fmaf(sc3[r], (float)L3[nt][r], b2r[r])));
                    const float vd = v2[p] + 0.1f * (i2[p] - v2[p]);
                    i2[p] = i2[p] * 0.8f + cur2;
                    const bool sp = vd > 1.0f;
                    v2[p] = sp ? 0.0f : vd;
                    zbits[r] = sp ? 0x3F80u : 0u;     // bf16 1.0
                }
                if (zv[nt]) {
                    const unsigned lo = zbits[0] | (zbits[1] << 16);
                    const unsigned hi = zbits[2] | (zbits[3] << 16);
                    *(uint2*)(z2b + zwo[nt]) = make_uint2(lo, hi);
                }
            }
        }
    };

    #pragma unroll 1
    for (int cc = 0; cc < NCHUNK; cc += 2) {
        chunk(cc, 0);
        chunk(cc + 1, 1);
    }

    __syncthreads();
    {   // final chunk (ch=49, P=1) fc
        const unsigned short* zp = s_z2h + 1 * Z2PAR + wave * Z2S;
        fc_step(zp, NSTEPS - 2);
        fc_step(zp + Z2T, NSTEPS - 1);
    }

    if (lane == 0)
        *(float2*)(out + (size_t)2 * sG) = make_float2(sum0, sum1);
}

extern "C" void kernel_launch(void* const* d_in, const int* in_sizes, int n_in,
                              void* d_out, int out_size, void* d_ws, size_t ws_size,
                              hipStream_t stream)
{
    const float* x  = (const float*)d_in[0];
    const float* w1 = (const float*)d_in[1];
    const float* b1 = (const float*)d_in[2];
    const float* w2 = (const float*)d_in[3];
    const float* b2 = (const float*)d_in[4];
    const float* wf = (const float*)d_in[5];
    const float* bf = (const float*)d_in[6];
    float* out = (float*)d_out;

    const int B = in_sizes[0] / 256;     // x is [B,1,16,16]
    const int grid = B / 4;              // 4 samples per block

    hipLaunchKernelGGL(snn_kernel, dim3(grid), dim3(256), 0, stream,
                       x, w1, b1, w2, b2, wf, bf, out, B);
}